// Round 4
// baseline (784.415 us; speedup 1.0000x reference)
//
#include <hip/hip_runtime.h>
#include <cstdint>
#include <cstddef>

// Problem constants
#define T_TOKENS 4096
#define DM 1024
#define DF 4096
#define NE 8
#define TOPK 2
#define MAX_MT 40   // max sum over experts of ceil(count_e/256); worst case 39
#define MSLOTS 8192 // TOPK * T_TOKENS

typedef short short8 __attribute__((ext_vector_type(8)));
typedef float f32x4 __attribute__((ext_vector_type(4)));

__device__ __forceinline__ unsigned short f2h_bits(float f) {
  _Float16 h = (_Float16)f;   // RNE
  union { _Float16 h; unsigned short u; } v; v.h = h; return v.u;
}

typedef __attribute__((address_space(3))) void lds_void_t;
typedef __attribute__((address_space(1))) void gvoid_t;
__device__ __forceinline__ void gl_lds16(const void* g, void* l) {
  __builtin_amdgcn_global_load_lds((gvoid_t*)g, (lds_void_t*)l, 16, 0, 0);
}

// ------------- gate: fp32 logits, top-2, softmax, histogram; also emit Xh fp16 -------------
__global__ void gate_kernel(const float* __restrict__ x, const float* __restrict__ Wg,
                            int* __restrict__ sel, float* __restrict__ wts,
                            int* __restrict__ counts, unsigned short* __restrict__ Xh) {
  int wave = threadIdx.x >> 6, lane = threadIdx.x & 63;
  int t = blockIdx.x * 4 + wave;
  const float* xr = x + (size_t)t * DM;
  unsigned short* xh = Xh + (size_t)t * DM;
  float acc[NE];
#pragma unroll
  for (int e = 0; e < NE; e++) acc[e] = 0.f;
#pragma unroll
  for (int j = 0; j < 4; j++) {
    int d4 = (lane + 64 * j) * 4;
    float4 v = *(const float4*)(xr + d4);
    ushort4 o;
    o.x = f2h_bits(v.x); o.y = f2h_bits(v.y); o.z = f2h_bits(v.z); o.w = f2h_bits(v.w);
    *(ushort4*)(xh + d4) = o;
    const float* wr = Wg + (size_t)d4 * NE;
#pragma unroll
    for (int e = 0; e < NE; e++) acc[e] += v.x * wr[e];
#pragma unroll
    for (int e = 0; e < NE; e++) acc[e] += v.y * wr[NE + e];
#pragma unroll
    for (int e = 0; e < NE; e++) acc[e] += v.z * wr[2 * NE + e];
#pragma unroll
    for (int e = 0; e < NE; e++) acc[e] += v.w * wr[3 * NE + e];
  }
#pragma unroll
  for (int e = 0; e < NE; e++) {
    float v = acc[e];
#pragma unroll
    for (int off = 32; off > 0; off >>= 1) v += __shfl_down(v, off, 64);
    acc[e] = v;
  }
  if (lane == 0) {
    int b0 = 0;
#pragma unroll
    for (int e = 1; e < NE; e++) if (acc[e] > acc[b0]) b0 = e;   // first-index tie-break
    int b1 = (b0 == 0) ? 1 : 0;
#pragma unroll
    for (int e = 0; e < NE; e++) if (e != b0 && acc[e] > acc[b1]) b1 = e;
    float p = expf(acc[b1] - acc[b0]);
    float w0 = 1.f / (1.f + p);
    sel[t * 2] = b0; sel[t * 2 + 1] = b1;
    wts[t * 2] = w0; wts[t * 2 + 1] = p * w0;
    atomicAdd(&counts[b0], 1);
    atomicAdd(&counts[b1], 1);
  }
}

// ---------------- scan: offsets, gemm tile offsets (256-granular), cursors ----------------
__global__ void scan_kernel(const int* __restrict__ counts, int* __restrict__ offsets,
                            int* __restrict__ tile_off, int* __restrict__ cursors) {
  if (threadIdx.x == 0) {
    int o = 0, to = 0;
    offsets[0] = 0; tile_off[0] = 0;
    for (int e = 0; e < NE; e++) {
      cursors[e] = o;
      o += counts[e];
      to += (counts[e] + 255) >> 8;
      offsets[e + 1] = o;
      tile_off[e + 1] = to;
    }
  }
}

// ---------------- scatter: token -> compacted slot lists + inverse map ----------------
__global__ void scatter_kernel(const int* __restrict__ sel, const float* __restrict__ wts,
                               int* __restrict__ cursors, int* __restrict__ rows,
                               float* __restrict__ rw, int* __restrict__ inv) {
  int t = blockIdx.x * 256 + threadIdx.x;
  if (t >= T_TOKENS) return;
#pragma unroll
  for (int k = 0; k < TOPK; k++) {
    int e = sel[t * 2 + k];
    int slot = atomicAdd(&cursors[e], 1);
    rows[slot] = t;
    rw[slot] = wts[t * 2 + k];
    inv[t * 2 + k] = slot;
  }
}

// ------- fp32 -> fp16 transpose, both weights in ONE launch -------
__global__ void transpose_convert(const float* __restrict__ W1, unsigned short* __restrict__ W1t,
                                  const float* __restrict__ W2, unsigned short* __restrict__ W2t) {
  __shared__ float tile[64 * 65];
  int z = blockIdx.y;
  int R, C;
  const float* inE;
  unsigned short* outE;
  int tidx = blockIdx.x;   // 1024 tiles per expert-matrix
  int bx, by;
  if (z < 8) {
    R = DM; C = DF;
    inE = W1 + (size_t)z * DM * DF;
    outE = W1t + (size_t)z * DM * DF;
    bx = tidx % (DF / 64); by = tidx / (DF / 64);
  } else {
    R = DF; C = DM;
    inE = W2 + (size_t)(z - 8) * DM * DF;
    outE = W2t + (size_t)(z - 8) * DM * DF;
    bx = tidx % (DM / 64); by = tidx / (DM / 64);
  }
  int c0 = bx * 64, r0 = by * 64;
  int tid = threadIdx.x;
  int rr = tid >> 4, c4 = (tid & 15) * 4;
#pragma unroll
  for (int it = 0; it < 4; it++) {
    int r = rr + 16 * it;
    float4 v = *(const float4*)(inE + (size_t)(r0 + r) * C + c0 + c4);
    tile[r * 65 + c4 + 0] = v.x;
    tile[r * 65 + c4 + 1] = v.y;
    tile[r * 65 + c4 + 2] = v.z;
    tile[r * 65 + c4 + 3] = v.w;
  }
  __syncthreads();
#pragma unroll
  for (int it = 0; it < 2; it++) {
    int idx = tid + 256 * it;           // 512 ushort8 units: c = idx>>3, r8 = (idx&7)*8
    int c = idx >> 3, r8 = (idx & 7) * 8;
    short8 val;
#pragma unroll
    for (int j = 0; j < 8; j++) val[j] = (short)f2h_bits(tile[(r8 + j) * 65 + c]);
    *(short8*)(outE + (size_t)(c0 + c) * R + r0 + r8) = val;
  }
}

// ---------------- grouped GEMM, 256x256 8-phase template: C = A(MxK) * Bt(NxK)^T ----------------
// 512 thr = 8 waves (2M x 4N), per-wave 128x64 out, BK=64, LDS 128KB = 2 bufs x 4 chunks
// (A_h0|B_h0|A_h1|B_h1, 16KB each; chunk = 256 rows x 32 cols fp16, 64B rows).
// Swizzle (rule 21, involution): chunk seg' = seg ^ (row&3); applied on global SOURCE at stage
// and on ds_read addr; gl_lds dest stays linear (base + tid*16). 2-way bank alias = free.
// Per K-tile u: 4 phases; phase g issues chunk g of K-tile u+1 into buf (u+1)&1, then
// counted s_waitcnt vmcnt(6) (even phases only; 3 chunks younger than the needed one),
// barrier, ds_read subtile, setprio(1)+16 MFMA+setprio(0), lgkmcnt(0)+barrier.
// Loads stay in flight 3 phases; NEVER vmcnt(0) in the main loop. Last K-tile wrap-stages
// K-tile 0 (harmless) to keep bookkeeping uniform; vmcnt(0) once before the epilogue.
template <int K, int N, int NT, int NSPLIT, bool INDIR, bool SECOND>
__global__ __launch_bounds__(512, 1) void moe_gemm(
    const unsigned short* __restrict__ Aall, const unsigned short* __restrict__ Ball,
    unsigned short* __restrict__ Hout, float* __restrict__ Sout,
    const float* __restrict__ bias, const int* __restrict__ counts,
    const int* __restrict__ offsets, const int* __restrict__ tile_off,
    const int* __restrict__ rows, const float* __restrict__ rw) {
  __shared__ __align__(16) unsigned short lds[65536];   // 128 KB

  int id = blockIdx.x;
  int nt = id % NT;               // consecutive ids -> different XCDs share the A m-tile
  int rest = id / NT;
  int ks = rest % NSPLIT;
  int bx = rest / NSPLIT;
  int e = 0;
#pragma unroll 1
  while (e < NE && bx >= tile_off[e + 1]) e++;
  if (e >= NE) return;
  int lt = bx - tile_off[e];
  int cnt = counts[e];
  int m0 = lt * 256;
  int rowbase = offsets[e];
  int n0 = nt * 256;

  const int KS = K / NSPLIT;      // 1024 (GEMM1) or 2048 (GEMM2 split-K)
  const int NKT = KS / 64;        // K-tiles of 64
  const int kbeg = ks * KS;

  int tid = threadIdx.x;
  int lane = tid & 63, wave = tid >> 6;
  int wm = wave >> 2, wn = wave & 3;             // 2M x 4N wave grid
  int quad = lane >> 4, c15 = lane & 15;

  // ---- staging: thread tid owns chunk seg idx tid (row=tid>>2, pseg=tid&3) and idx 512+tid
  // (row+128, same pseg). Source logical seg l = pseg ^ (row&3); rows 128 apart share l.
  int srow = tid >> 2;                           // 0..127
  int l8 = ((tid & 3) ^ (srow & 3)) * 8;         // swizzled source col offset (shorts)
  int ma0 = m0 + srow;        if (ma0 >= cnt) ma0 = cnt - 1;
  int ma1 = m0 + 128 + srow;  if (ma1 >= cnt) ma1 = cnt - 1;
  size_t ia0 = INDIR ? (size_t)rows[rowbase + ma0] : (size_t)(rowbase + ma0);
  size_t ia1 = INDIR ? (size_t)rows[rowbase + ma1] : (size_t)(rowbase + ma1);
  const unsigned short* pA0 = Aall + ia0 * K + kbeg + l8;
  const unsigned short* pA1 = Aall + ia1 * K + kbeg + l8;
  const unsigned short* pB0 = Ball + ((size_t)e * N + n0 + srow) * K + kbeg + l8;
  const unsigned short* pB1 = pB0 + (size_t)128 * K;

  // ---- fragment read bases: pseg = quad ^ (row&3) = quad ^ (c15&3) (rows stride mult of 16)
  int sp8 = (quad ^ (c15 & 3)) * 8;
  int aBase = (wm * 128 + c15) * 32 + sp8;          // + mg*512 + h*16384 + buf*32768
  int bBase = (wn * 64  + c15) * 32 + sp8 + 8192;   // + n*512  + h*16384 + buf*32768

  f32x4 acc[8][4] = {};

  auto stageA = [&](int buf, int v, int h) {
    unsigned short* b = lds + buf * 32768 + h * 16384;
    int ko = v * 64 + h * 32;
    gl_lds16(pA0 + ko, b + tid * 8);
    gl_lds16(pA1 + ko, b + 4096 + tid * 8);
  };
  auto stageB = [&](int buf, int v, int h) {
    unsigned short* b = lds + buf * 32768 + h * 16384 + 8192;
    int ko = v * 64 + h * 32;
    gl_lds16(pB0 + ko, b + tid * 8);
    gl_lds16(pB1 + ko, b + 4096 + tid * 8);
  };

  // prologue: K-tile 0 fully staged, issue order A_h0, B_h0, A_h1, B_h1 (8 loads in flight)
  stageA(0, 0, 0); stageB(0, 0, 0); stageA(0, 0, 1); stageB(0, 0, 1);

#pragma unroll 1
  for (int u = 0; u < NKT; ++u) {
    int p = u & 1;
    int v = (u + 1 < NKT) ? u + 1 : 0;   // wrap-stage: keeps vmcnt bookkeeping uniform
#pragma unroll
    for (int h = 0; h < 2; ++h) {
      const unsigned short* L = lds + p * 32768 + h * 16384;
      short8 bf[4], af[4];
      // ---- even phase: stage A[u+1,h]; vmcnt(6) -> A[u,h],B[u,h] resident; m0-3 MFMA ----
      stageA(p ^ 1, v, h);
      asm volatile("s_waitcnt vmcnt(6)" ::: "memory");
      __builtin_amdgcn_s_barrier();
#pragma unroll
      for (int n = 0; n < 4; ++n) bf[n] = *(const short8*)(L + bBase + n * 512);
#pragma unroll
      for (int m = 0; m < 4; ++m) af[m] = *(const short8*)(L + aBase + m * 512);
      __builtin_amdgcn_s_setprio(1);
#pragma unroll
      for (int m = 0; m < 4; ++m)
#pragma unroll
        for (int n = 0; n < 4; ++n)
          acc[m][n] = __builtin_amdgcn_mfma_f32_16x16x32_f16(af[m], bf[n], acc[m][n], 0, 0, 0);
      __builtin_amdgcn_s_setprio(0);
      asm volatile("s_waitcnt lgkmcnt(0)" ::: "memory");
      __builtin_amdgcn_sched_barrier(0);
      __builtin_amdgcn_s_barrier();
      // ---- odd phase: stage B[u+1,h]; no vmcnt; m4-7 MFMA (bf reused) ----
      stageB(p ^ 1, v, h);
      __builtin_amdgcn_s_barrier();
#pragma unroll
      for (int m = 0; m < 4; ++m) af[m] = *(const short8*)(L + aBase + (4 + m) * 512);
      __builtin_amdgcn_s_setprio(1);
#pragma unroll
      for (int m = 0; m < 4; ++m)
#pragma unroll
        for (int n = 0; n < 4; ++n)
          acc[4 + m][n] = __builtin_amdgcn_mfma_f32_16x16x32_f16(af[m], bf[n], acc[4 + m][n], 0, 0, 0);
      __builtin_amdgcn_s_setprio(0);
      asm volatile("s_waitcnt lgkmcnt(0)" ::: "memory");
      __builtin_amdgcn_sched_barrier(0);
      __builtin_amdgcn_s_barrier();
    }
  }
  // drain wrap-stage loads before reusing LDS / exiting
  asm volatile("s_waitcnt vmcnt(0)" ::: "memory");
  __builtin_amdgcn_s_barrier();

  // epilogue: C/D layout col=lane&15, row=(lane>>4)*4+reg
  if constexpr (!SECOND) {
    // restage 64 output rows per round in LDS (stride 264), coalesced short8 stores
#pragma unroll 1
    for (int q = 0; q < 4; ++q) {
      if ((q >> 1) == wm) {
        int mb = (q & 1) * 4;
#pragma unroll
        for (int m = 0; m < 4; ++m) {
#pragma unroll
          for (int n = 0; n < 4; ++n) {
            int colL = wn * 64 + n * 16 + c15;
            float b = bias[e * N + n0 + colL];
#pragma unroll
            for (int r = 0; r < 4; ++r) {
              int rl = m * 16 + quad * 4 + r;   // 0..63
              float v = fmaxf(acc[mb + m][n][r] + b, 0.f);
              lds[rl * 264 + colL] = f2h_bits(v);
            }
          }
        }
      }
      __syncthreads();
#pragma unroll
      for (int i = 0; i < 4; ++i) {
        int idx = tid + 512 * i;                 // 2048 short8 units = 64 x 256
        int row = idx >> 5, c8 = (idx & 31) * 8;
        int grow = m0 + q * 64 + row;
        if (grow < cnt) {
          short8 val = *(const short8*)(lds + row * 264 + c8);
          *(short8*)(Hout + (size_t)(rowbase + grow) * N + n0 + c8) = val;
        }
      }
      __syncthreads();
    }
  } else {
    float* So = Sout + (size_t)ks * ((size_t)MSLOTS * N);
#pragma unroll
    for (int m = 0; m < 8; ++m) {
#pragma unroll
      for (int n = 0; n < 4; ++n) {
        int gcol = n0 + wn * 64 + n * 16 + c15;
        float b = (ks == 0) ? bias[e * N + gcol] : 0.f;
#pragma unroll
        for (int r = 0; r < 4; ++r) {
          int rl = wm * 128 + m * 16 + quad * 4 + r;
          if (m0 + rl < cnt) {
            int slot = rowbase + m0 + rl;
            So[(size_t)slot * N + gcol] = (acc[m][n][r] + b) * rw[slot];
          }
        }
      }
    }
  }
}

// ---------------- combine: out[t] = sum over split-K partials of both picked slots ----------------
__global__ void combine_kernel(const float* __restrict__ S, const int* __restrict__ inv,
                               float* __restrict__ out) {
  int wave = threadIdx.x >> 6, lane = threadIdx.x & 63;
  int t = blockIdx.x * 4 + wave;
  int s0 = inv[t * 2], s1 = inv[t * 2 + 1];
  const size_t HALF4 = (size_t)MSLOTS * DM / 4;   // float4 units between split-K partials
  const float4* a0 = (const float4*)S + (size_t)s0 * (DM / 4);
  const float4* a1 = a0 + HALF4;
  const float4* b0 = (const float4*)S + (size_t)s1 * (DM / 4);
  const float4* b1 = b0 + HALF4;
  float4* o = (float4*)(out + (size_t)t * DM);
#pragma unroll
  for (int j = 0; j < 4; j++) {
    int i = lane + 64 * j;
    float4 va = a0[i], vb = a1[i], vc = b0[i], vd = b1[i];
    float4 vo;
    vo.x = (va.x + vb.x) + (vc.x + vd.x);
    vo.y = (va.y + vb.y) + (vc.y + vd.y);
    vo.z = (va.z + vb.z) + (vc.z + vd.z);
    vo.w = (va.w + vb.w) + (vc.w + vd.w);
    o[i] = vo;
  }
}

extern "C" void kernel_launch(void* const* d_in, const int* in_sizes, int n_in,
                              void* d_out, int out_size, void* d_ws, size_t ws_size,
                              hipStream_t stream) {
  const float* x  = (const float*)d_in[0];
  const float* Wg = (const float*)d_in[1];
  const float* W1 = (const float*)d_in[2];
  const float* b1 = (const float*)d_in[3];
  const float* W2 = (const float*)d_in[4];
  const float* b2 = (const float*)d_in[5];
  float* out = (float*)d_out;

  char* ws = (char*)d_ws;
  int*   counts   = (int*)(ws + 0);
  int*   cursors  = (int*)(ws + 64);
  int*   offsets  = (int*)(ws + 128);
  int*   tile_off = (int*)(ws + 192);
  int*   sel      = (int*)(ws + 256);                  // 32 KB
  float* wts      = (float*)(ws + 33024);              // 32 KB
  int*   rows     = (int*)(ws + 65792);                // 32 KB
  float* rw       = (float*)(ws + 98560);              // 32 KB
  int*   inv      = (int*)(ws + 131328);               // 32 KB
  unsigned short* Xh  = (unsigned short*)(ws + 164096);                    // 8.39 MB
  unsigned short* H   = (unsigned short*)(ws + 8552704);                   // 67.1 MB
  unsigned short* W1t = (unsigned short*)(ws + 75661568);                  // 67.1 MB
  float*          S   = (float*)(ws + 75661568);                           // aliases W1t (dead after GEMM1); S0+S1 = 67.1 MB exactly
  unsigned short* W2t = (unsigned short*)(ws + 142770432);                 // 67.1 MB; end = 209.9 MB

  hipMemsetAsync(ws, 0, 128, stream);   // counts + cursors

  gate_kernel<<<T_TOKENS / 4, 256, 0, stream>>>(x, Wg, sel, wts, counts, Xh);
  scan_kernel<<<1, 64, 0, stream>>>(counts, offsets, tile_off, cursors);
  scatter_kernel<<<T_TOKENS / 256, 256, 0, stream>>>(sel, wts, cursors, rows, rw, inv);
  // W1 (E, D, F) -> W1t (E, F, D);  W2 (E, F, D) -> W2t (E, D, F), single launch
  transpose_convert<<<dim3(1024, 16), 256, 0, stream>>>(W1, W1t, W2, W2t);

  moe_gemm<DM, DF, 16, 1, true, false><<<MAX_MT * 16, 512, 0, stream>>>(
      Xh, W1t, H, nullptr, b1, counts, offsets, tile_off, rows, rw);
  moe_gemm<DF, DM, 4, 2, false, true><<<MAX_MT * 4 * 2, 512, 0, stream>>>(
      H, W2t, nullptr, S, b2, counts, offsets, tile_off, rows, rw);

  combine_kernel<<<T_TOKENS / 4, 256, 0, stream>>>(S, inv, out);
}

// Round 5
// 689.254 us; speedup vs baseline: 1.1381x; 1.1381x over previous
//
#include <hip/hip_runtime.h>
#include <cstdint>
#include <cstddef>

// Problem constants
#define T_TOKENS 4096
#define DM 1024
#define DF 4096
#define NE 8
#define TOPK 2
#define MAX_MT 40   // max sum over experts of ceil(count_e/256); worst case 39
#define MSLOTS 8192 // TOPK * T_TOKENS

typedef short short8 __attribute__((ext_vector_type(8)));
typedef float f32x4 __attribute__((ext_vector_type(4)));

__device__ __forceinline__ unsigned short f2h_bits(float f) {
  _Float16 h = (_Float16)f;   // RNE
  union { _Float16 h; unsigned short u; } v; v.h = h; return v.u;
}

typedef __attribute__((address_space(3))) void lds_void_t;
typedef __attribute__((address_space(1))) void gvoid_t;
__device__ __forceinline__ void gl_lds16(const void* g, void* l) {
  __builtin_amdgcn_global_load_lds((gvoid_t*)g, (lds_void_t*)l, 16, 0, 0);
}

// ------------- gate: fp32 logits, top-2, softmax, histogram; also emit Xh fp16 -------------
__global__ void gate_kernel(const float* __restrict__ x, const float* __restrict__ Wg,
                            int* __restrict__ sel, float* __restrict__ wts,
                            int* __restrict__ counts, unsigned short* __restrict__ Xh) {
  int wave = threadIdx.x >> 6, lane = threadIdx.x & 63;
  int t = blockIdx.x * 4 + wave;
  const float* xr = x + (size_t)t * DM;
  unsigned short* xh = Xh + (size_t)t * DM;
  float acc[NE];
#pragma unroll
  for (int e = 0; e < NE; e++) acc[e] = 0.f;
#pragma unroll
  for (int j = 0; j < 4; j++) {
    int d4 = (lane + 64 * j) * 4;
    float4 v = *(const float4*)(xr + d4);
    ushort4 o;
    o.x = f2h_bits(v.x); o.y = f2h_bits(v.y); o.z = f2h_bits(v.z); o.w = f2h_bits(v.w);
    *(ushort4*)(xh + d4) = o;
    const float* wr = Wg + (size_t)d4 * NE;
#pragma unroll
    for (int e = 0; e < NE; e++) acc[e] += v.x * wr[e];
#pragma unroll
    for (int e = 0; e < NE; e++) acc[e] += v.y * wr[NE + e];
#pragma unroll
    for (int e = 0; e < NE; e++) acc[e] += v.z * wr[2 * NE + e];
#pragma unroll
    for (int e = 0; e < NE; e++) acc[e] += v.w * wr[3 * NE + e];
  }
#pragma unroll
  for (int e = 0; e < NE; e++) {
    float v = acc[e];
#pragma unroll
    for (int off = 32; off > 0; off >>= 1) v += __shfl_down(v, off, 64);
    acc[e] = v;
  }
  if (lane == 0) {
    int b0 = 0;
#pragma unroll
    for (int e = 1; e < NE; e++) if (acc[e] > acc[b0]) b0 = e;   // first-index tie-break
    int b1 = (b0 == 0) ? 1 : 0;
#pragma unroll
    for (int e = 0; e < NE; e++) if (e != b0 && acc[e] > acc[b1]) b1 = e;
    float p = expf(acc[b1] - acc[b0]);
    float w0 = 1.f / (1.f + p);
    sel[t * 2] = b0; sel[t * 2 + 1] = b1;
    wts[t * 2] = w0; wts[t * 2 + 1] = p * w0;
    atomicAdd(&counts[b0], 1);
    atomicAdd(&counts[b1], 1);
  }
}

// ---------------- scan: offsets, gemm tile offsets (256-granular), cursors ----------------
__global__ void scan_kernel(const int* __restrict__ counts, int* __restrict__ offsets,
                            int* __restrict__ tile_off, int* __restrict__ cursors) {
  if (threadIdx.x == 0) {
    int o = 0, to = 0;
    offsets[0] = 0; tile_off[0] = 0;
    for (int e = 0; e < NE; e++) {
      cursors[e] = o;
      o += counts[e];
      to += (counts[e] + 255) >> 8;
      offsets[e + 1] = o;
      tile_off[e + 1] = to;
    }
  }
}

// ---------------- scatter: token -> compacted slot lists + inverse map ----------------
__global__ void scatter_kernel(const int* __restrict__ sel, const float* __restrict__ wts,
                               int* __restrict__ cursors, int* __restrict__ rows,
                               float* __restrict__ rw, int* __restrict__ inv) {
  int t = blockIdx.x * 256 + threadIdx.x;
  if (t >= T_TOKENS) return;
#pragma unroll
  for (int k = 0; k < TOPK; k++) {
    int e = sel[t * 2 + k];
    int slot = atomicAdd(&cursors[e], 1);
    rows[slot] = t;
    rw[slot] = wts[t * 2 + k];
    inv[t * 2 + k] = slot;
  }
}

// ------- fp32 -> fp16 transpose, both weights in ONE launch -------
__global__ void transpose_convert(const float* __restrict__ W1, unsigned short* __restrict__ W1t,
                                  const float* __restrict__ W2, unsigned short* __restrict__ W2t) {
  __shared__ float tile[64 * 65];
  int z = blockIdx.y;
  int R, C;
  const float* inE;
  unsigned short* outE;
  int tidx = blockIdx.x;   // 1024 tiles per expert-matrix
  int bx, by;
  if (z < 8) {
    R = DM; C = DF;
    inE = W1 + (size_t)z * DM * DF;
    outE = W1t + (size_t)z * DM * DF;
    bx = tidx % (DF / 64); by = tidx / (DF / 64);
  } else {
    R = DF; C = DM;
    inE = W2 + (size_t)(z - 8) * DM * DF;
    outE = W2t + (size_t)(z - 8) * DM * DF;
    bx = tidx % (DM / 64); by = tidx / (DM / 64);
  }
  int c0 = bx * 64, r0 = by * 64;
  int tid = threadIdx.x;
  int rr = tid >> 4, c4 = (tid & 15) * 4;
#pragma unroll
  for (int it = 0; it < 4; it++) {
    int r = rr + 16 * it;
    float4 v = *(const float4*)(inE + (size_t)(r0 + r) * C + c0 + c4);
    tile[r * 65 + c4 + 0] = v.x;
    tile[r * 65 + c4 + 1] = v.y;
    tile[r * 65 + c4 + 2] = v.z;
    tile[r * 65 + c4 + 3] = v.w;
  }
  __syncthreads();
#pragma unroll
  for (int it = 0; it < 2; it++) {
    int idx = tid + 256 * it;           // 512 ushort8 units: c = idx>>3, r8 = (idx&7)*8
    int c = idx >> 3, r8 = (idx & 7) * 8;
    short8 val;
#pragma unroll
    for (int j = 0; j < 8; j++) val[j] = (short)f2h_bits(tile[(r8 + j) * 65 + c]);
    *(short8*)(outE + (size_t)(c0 + c) * R + r0 + r8) = val;
  }
}

// ---------------- grouped GEMM, 256x256 8-phase template: C = A(MxK) * Bt(NxK)^T ----------------
// 512 thr = 8 waves (2M x 4N), per-wave 128x64 out, BK=64, LDS 128KB = 2 bufs x 4 chunks
// (A_h0|B_h0|A_h1|B_h1, 16KB each; chunk = 256 rows x 32 cols fp16, 64B rows).
// Swizzle (rule 21, involution): chunk seg' = seg ^ ((row>>1)&3) -- bank = (16*row + 4*seg)%32,
// row contributes only parity, so seg must cycle with (row>>1) to cover all 8 bank-groups.
// (round-2/3 formula: measured ZERO conflicts; (row&3) variant measured 6.88M - do not use.)
// Applied on global SOURCE at stage + on ds_read addr; gl_lds dest stays linear.
// Per K-tile u: 4 phases; even phase stages A[u+1,h], waits vmcnt(6) (3 chunk-pairs younger
// than the needed pair), barrier, ds_read, setprio(1)+16 MFMA+setprio(0), lgkm(0)+barrier;
// odd phase stages B[u+1,h], no vmcnt. NEVER vmcnt(0) in the main loop. Last K-tile
// wrap-stages K-tile 0 to keep bookkeeping uniform; vmcnt(0) once before the epilogue.
// RULE #20: every acc[][] index must be compile-time (epilogue q-loop FULLY unrolled;
// the round-4 `#pragma unroll 1` there sent acc to scratch: VGPR 96, WRITE_SIZE 352MB).
template <int K, int N, int NT, int NSPLIT, bool INDIR, bool SECOND>
__global__ __launch_bounds__(512, 1) void moe_gemm(
    const unsigned short* __restrict__ Aall, const unsigned short* __restrict__ Ball,
    unsigned short* __restrict__ Hout, float* __restrict__ Sout,
    const float* __restrict__ bias, const int* __restrict__ counts,
    const int* __restrict__ offsets, const int* __restrict__ tile_off,
    const int* __restrict__ rows, const float* __restrict__ rw) {
  __shared__ __align__(16) unsigned short lds[65536];   // 128 KB

  int id = blockIdx.x;
  int nt = id % NT;               // consecutive ids -> different XCDs share the A m-tile
  int rest = id / NT;
  int ks = rest % NSPLIT;
  int bx = rest / NSPLIT;
  int e = 0;
#pragma unroll 1
  while (e < NE && bx >= tile_off[e + 1]) e++;
  if (e >= NE) return;
  int lt = bx - tile_off[e];
  int cnt = counts[e];
  int m0 = lt * 256;
  int rowbase = offsets[e];
  int n0 = nt * 256;

  const int KS = K / NSPLIT;      // 1024 (GEMM1) or 2048 (GEMM2 split-K)
  const int NKT = KS / 64;        // K-tiles of 64
  const int kbeg = ks * KS;

  int tid = threadIdx.x;
  int lane = tid & 63, wave = tid >> 6;
  int wm = wave >> 2, wn = wave & 3;             // 2M x 4N wave grid
  int quad = lane >> 4, c15 = lane & 15;

  // ---- staging: thread tid owns chunk seg idx tid (row=tid>>2, pseg=tid&3) and idx 512+tid
  // (row+128, same pseg). Source logical seg l = pseg ^ ((row>>1)&3); rows 128 apart share l
  // (128>>1 = 64 == 0 mod 4).
  int srow = tid >> 2;                           // 0..127
  int l8 = ((tid & 3) ^ ((srow >> 1) & 3)) * 8;  // swizzled source col offset (shorts)
  int ma0 = m0 + srow;        if (ma0 >= cnt) ma0 = cnt - 1;
  int ma1 = m0 + 128 + srow;  if (ma1 >= cnt) ma1 = cnt - 1;
  size_t ia0 = INDIR ? (size_t)rows[rowbase + ma0] : (size_t)(rowbase + ma0);
  size_t ia1 = INDIR ? (size_t)rows[rowbase + ma1] : (size_t)(rowbase + ma1);
  const unsigned short* pA0 = Aall + ia0 * K + kbeg + l8;
  const unsigned short* pA1 = Aall + ia1 * K + kbeg + l8;
  const unsigned short* pB0 = Ball + ((size_t)e * N + n0 + srow) * K + kbeg + l8;
  const unsigned short* pB1 = pB0 + (size_t)128 * K;

  // ---- fragment read bases: row = (16-mult) + c15 -> (row>>1)&3 = (c15>>1)&3
  int sp8 = (quad ^ ((c15 >> 1) & 3)) * 8;
  int aBase = (wm * 128 + c15) * 32 + sp8;          // + mg*512 + h*16384 + buf*32768
  int bBase = (wn * 64  + c15) * 32 + sp8 + 8192;   // + n*512  + h*16384 + buf*32768

  f32x4 acc[8][4] = {};

  auto stageA = [&](int buf, int v, int h) {
    unsigned short* b = lds + buf * 32768 + h * 16384;
    int ko = v * 64 + h * 32;
    gl_lds16(pA0 + ko, b + tid * 8);
    gl_lds16(pA1 + ko, b + 4096 + tid * 8);
  };
  auto stageB = [&](int buf, int v, int h) {
    unsigned short* b = lds + buf * 32768 + h * 16384 + 8192;
    int ko = v * 64 + h * 32;
    gl_lds16(pB0 + ko, b + tid * 8);
    gl_lds16(pB1 + ko, b + 4096 + tid * 8);
  };

  // prologue: K-tile 0 fully staged, issue order A_h0, B_h0, A_h1, B_h1 (8 loads in flight)
  stageA(0, 0, 0); stageB(0, 0, 0); stageA(0, 0, 1); stageB(0, 0, 1);

#pragma unroll 1
  for (int u = 0; u < NKT; ++u) {
    int p = u & 1;
    int v = (u + 1 < NKT) ? u + 1 : 0;   // wrap-stage: keeps vmcnt bookkeeping uniform
#pragma unroll
    for (int h = 0; h < 2; ++h) {
      const unsigned short* L = lds + p * 32768 + h * 16384;
      short8 bf[4], af[4];
      // ---- even phase: stage A[u+1,h]; vmcnt(6) -> A[u,h],B[u,h] resident; m0-3 MFMA ----
      stageA(p ^ 1, v, h);
      asm volatile("s_waitcnt vmcnt(6)" ::: "memory");
      __builtin_amdgcn_s_barrier();
#pragma unroll
      for (int n = 0; n < 4; ++n) bf[n] = *(const short8*)(L + bBase + n * 512);
#pragma unroll
      for (int m = 0; m < 4; ++m) af[m] = *(const short8*)(L + aBase + m * 512);
      __builtin_amdgcn_s_setprio(1);
#pragma unroll
      for (int m = 0; m < 4; ++m)
#pragma unroll
        for (int n = 0; n < 4; ++n)
          acc[m][n] = __builtin_amdgcn_mfma_f32_16x16x32_f16(af[m], bf[n], acc[m][n], 0, 0, 0);
      __builtin_amdgcn_s_setprio(0);
      asm volatile("s_waitcnt lgkmcnt(0)" ::: "memory");
      __builtin_amdgcn_sched_barrier(0);
      __builtin_amdgcn_s_barrier();
      // ---- odd phase: stage B[u+1,h]; no vmcnt; m4-7 MFMA (bf reused) ----
      stageB(p ^ 1, v, h);
      __builtin_amdgcn_s_barrier();
#pragma unroll
      for (int m = 0; m < 4; ++m) af[m] = *(const short8*)(L + aBase + (4 + m) * 512);
      __builtin_amdgcn_s_setprio(1);
#pragma unroll
      for (int m = 0; m < 4; ++m)
#pragma unroll
        for (int n = 0; n < 4; ++n)
          acc[4 + m][n] = __builtin_amdgcn_mfma_f32_16x16x32_f16(af[m], bf[n], acc[4 + m][n], 0, 0, 0);
      __builtin_amdgcn_s_setprio(0);
      asm volatile("s_waitcnt lgkmcnt(0)" ::: "memory");
      __builtin_amdgcn_sched_barrier(0);
      __builtin_amdgcn_s_barrier();
    }
  }
  // drain wrap-stage loads before reusing LDS / exiting
  asm volatile("s_waitcnt vmcnt(0)" ::: "memory");
  __builtin_amdgcn_s_barrier();

  // epilogue: C/D layout col=lane&15, row=(lane>>4)*4+reg
  if constexpr (!SECOND) {
    // restage 64 output rows per round in LDS (stride 264), coalesced short8 stores.
    // q FULLY unrolled so acc indices are compile-time constants (rule #20).
#pragma unroll
    for (int q = 0; q < 4; ++q) {
      if ((q >> 1) == wm) {
        const int mb = (q & 1) * 4;
#pragma unroll
        for (int m = 0; m < 4; ++m) {
#pragma unroll
          for (int n = 0; n < 4; ++n) {
            int colL = wn * 64 + n * 16 + c15;
            float b = bias[e * N + n0 + colL];
#pragma unroll
            for (int r = 0; r < 4; ++r) {
              int rl = m * 16 + quad * 4 + r;   // 0..63
              float v = fmaxf(acc[mb + m][n][r] + b, 0.f);
              lds[rl * 264 + colL] = f2h_bits(v);
            }
          }
        }
      }
      __syncthreads();
#pragma unroll
      for (int i = 0; i < 4; ++i) {
        int idx = tid + 512 * i;                 // 2048 short8 units = 64 x 256
        int row = idx >> 5, c8 = (idx & 31) * 8;
        int grow = m0 + q * 64 + row;
        if (grow < cnt) {
          short8 val = *(const short8*)(lds + row * 264 + c8);
          *(short8*)(Hout + (size_t)(rowbase + grow) * N + n0 + c8) = val;
        }
      }
      __syncthreads();
    }
  } else {
    float* So = Sout + (size_t)ks * ((size_t)MSLOTS * N);
#pragma unroll
    for (int m = 0; m < 8; ++m) {
#pragma unroll
      for (int n = 0; n < 4; ++n) {
        int gcol = n0 + wn * 64 + n * 16 + c15;
        float b = (ks == 0) ? bias[e * N + gcol] : 0.f;
#pragma unroll
        for (int r = 0; r < 4; ++r) {
          int rl = wm * 128 + m * 16 + quad * 4 + r;
          if (m0 + rl < cnt) {
            int slot = rowbase + m0 + rl;
            So[(size_t)slot * N + gcol] = (acc[m][n][r] + b) * rw[slot];
          }
        }
      }
    }
  }
}

// ---------------- combine: out[t] = sum over split-K partials of both picked slots ----------------
__global__ void combine_kernel(const float* __restrict__ S, const int* __restrict__ inv,
                               float* __restrict__ out) {
  int wave = threadIdx.x >> 6, lane = threadIdx.x & 63;
  int t = blockIdx.x * 4 + wave;
  int s0 = inv[t * 2], s1 = inv[t * 2 + 1];
  const size_t HALF4 = (size_t)MSLOTS * DM / 4;   // float4 units between split-K partials
  const float4* a0 = (const float4*)S + (size_t)s0 * (DM / 4);
  const float4* a1 = a0 + HALF4;
  const float4* b0 = (const float4*)S + (size_t)s1 * (DM / 4);
  const float4* b1 = b0 + HALF4;
  float4* o = (float4*)(out + (size_t)t * DM);
#pragma unroll
  for (int j = 0; j < 4; j++) {
    int i = lane + 64 * j;
    float4 va = a0[i], vb = a1[i], vc = b0[i], vd = b1[i];
    float4 vo;
    vo.x = (va.x + vb.x) + (vc.x + vd.x);
    vo.y = (va.y + vb.y) + (vc.y + vd.y);
    vo.z = (va.z + vb.z) + (vc.z + vd.z);
    vo.w = (va.w + vb.w) + (vc.w + vd.w);
    o[i] = vo;
  }
}

extern "C" void kernel_launch(void* const* d_in, const int* in_sizes, int n_in,
                              void* d_out, int out_size, void* d_ws, size_t ws_size,
                              hipStream_t stream) {
  const float* x  = (const float*)d_in[0];
  const float* Wg = (const float*)d_in[1];
  const float* W1 = (const float*)d_in[2];
  const float* b1 = (const float*)d_in[3];
  const float* W2 = (const float*)d_in[4];
  const float* b2 = (const float*)d_in[5];
  float* out = (float*)d_out;

  char* ws = (char*)d_ws;
  int*   counts   = (int*)(ws + 0);
  int*   cursors  = (int*)(ws + 64);
  int*   offsets  = (int*)(ws + 128);
  int*   tile_off = (int*)(ws + 192);
  int*   sel      = (int*)(ws + 256);                  // 32 KB
  float* wts      = (float*)(ws + 33024);              // 32 KB
  int*   rows     = (int*)(ws + 65792);                // 32 KB
  float* rw       = (float*)(ws + 98560);              // 32 KB
  int*   inv      = (int*)(ws + 131328);               // 32 KB
  unsigned short* Xh  = (unsigned short*)(ws + 164096);                    // 8.39 MB
  unsigned short* H   = (unsigned short*)(ws + 8552704);                   // 67.1 MB
  unsigned short* W1t = (unsigned short*)(ws + 75661568);                  // 67.1 MB
  float*          S   = (float*)(ws + 75661568);                           // aliases W1t (dead after GEMM1); S0+S1 = 67.1 MB exactly
  unsigned short* W2t = (unsigned short*)(ws + 142770432);                 // 67.1 MB; end = 209.9 MB

  hipMemsetAsync(ws, 0, 128, stream);   // counts + cursors

  gate_kernel<<<T_TOKENS / 4, 256, 0, stream>>>(x, Wg, sel, wts, counts, Xh);
  scan_kernel<<<1, 64, 0, stream>>>(counts, offsets, tile_off, cursors);
  scatter_kernel<<<T_TOKENS / 256, 256, 0, stream>>>(sel, wts, cursors, rows, rw, inv);
  // W1 (E, D, F) -> W1t (E, F, D);  W2 (E, F, D) -> W2t (E, D, F), single launch
  transpose_convert<<<dim3(1024, 16), 256, 0, stream>>>(W1, W1t, W2, W2t);

  moe_gemm<DM, DF, 16, 1, true, false><<<MAX_MT * 16, 512, 0, stream>>>(
      Xh, W1t, H, nullptr, b1, counts, offsets, tile_off, rows, rw);
  moe_gemm<DF, DM, 4, 2, false, true><<<MAX_MT * 4 * 2, 512, 0, stream>>>(
      H, W2t, nullptr, S, b2, counts, offsets, tile_off, rows, rw);

  combine_kernel<<<T_TOKENS / 4, 256, 0, stream>>>(S, inv, out);
}